// Round 6
// baseline (243.302 us; speedup 1.0000x reference)
//
#include <hip/hip_runtime.h>
#include <stdint.h>

typedef unsigned int uint;

#define HW 3600
#define NBATCH 2
#define CDIM 256
#define KNN 64
#define M_REAL 7200
#define PADM 7232          // 7200 padded to multiple of 64 (113*64)
#define QPB 8              // topk queries per block (one per wave)

using short8  = __attribute__((ext_vector_type(8))) short;
using floatx4 = __attribute__((ext_vector_type(4))) float;

__device__ inline unsigned short f2bf(float f) {   // RNE fp32 -> bf16 bits
    uint u = __float_as_uint(f);
    uint r = u + 0x7FFFu + ((u >> 16) & 1u);
    return (unsigned short)(r >> 16);
}
__device__ inline float bf2f(unsigned short b) {
    return __uint_as_float(((uint)b) << 16);
}

// ---------------------------------------------------------------------------
// Top-K: 512-thread blocks, 8 queries/block (one per wave). Points staged in
// LDS planar x/y/z; distance pass reads them as float4 (ds_read_b128, 4
// points/lane) — halves DS-pipe issue vs b32 (round-5 bottleneck).
// Phases separated by block-wide barriers (block-uniform control flow;
// the barrier-free variant faulted in round 4).
// Two 8-bit radix passes on linearly-quantized 16-bit keys; exact-key ties.
// Point (c,t) of lane: j = c*256 + lane*4 + t, c in [0,15), t in [0,4).
// ---------------------------------------------------------------------------
__device__ inline void wave_select(uint* hist, uint* s_bin, uint* s_want,
                                   int lane, uint want) {
    uint h0 = hist[4 * lane + 0], h1 = hist[4 * lane + 1];
    uint h2 = hist[4 * lane + 2], h3 = hist[4 * lane + 3];
    hist[4 * lane + 0] = 0; hist[4 * lane + 1] = 0;
    hist[4 * lane + 2] = 0; hist[4 * lane + 3] = 0;
    uint c4 = h0 + h1 + h2 + h3;
    uint v = c4;
    #pragma unroll
    for (int off = 1; off < 64; off <<= 1) {
        uint o = __shfl_up(v, off, 64);
        if (lane >= off) v += o;
    }
    uint below = v - c4;                 // count in bins < 4*lane
    if (below < want && want <= v) {     // threshold bin is in my 4 bins
        uint b = 4 * lane, c = below;
        if (c + h0 < want) { c += h0; b = 4 * lane + 1;
            if (c + h1 < want) { c += h1; b = 4 * lane + 2;
                if (c + h2 < want) { c += h2; b = 4 * lane + 3; } } }
        *s_bin = b;
        *s_want = want - c;
    }
}

__global__ __launch_bounds__(512) void topk_kernel(const float* __restrict__ points,
                                                   int* __restrict__ idx_out) {
    const int wv = threadIdx.x >> 6;
    const int lane = threadIdx.x & 63;
    const int q = blockIdx.x * QPB + wv;
    const int n = (blockIdx.x * QPB) / HW;     // batch uniform per block (450 | 8)
    const int i = q - n * HW;

    __shared__ __align__(16) float sx[HW], sy[HW], sz[HW];   // 43200 B
    __shared__ uint hist[QPB][256];                          // 8192 B
    __shared__ uint s_bin[QPB], s_want[QPB], s_cnt[QPB];

    const float* __restrict__ px = points + (size_t)n * 3 * HW;

    // staged as float4 (900 per plane)
    for (int j4 = threadIdx.x; j4 < HW / 4; j4 += 512) {
        *(float4*)&sx[j4 * 4] = ((const float4*)px)[j4];
        *(float4*)&sy[j4 * 4] = ((const float4*)px)[j4 + HW / 4];
        *(float4*)&sz[j4 * 4] = ((const float4*)px)[j4 + 2 * (HW / 4)];
    }
    hist[wv][4 * lane + 0] = 0; hist[wv][4 * lane + 1] = 0;
    hist[wv][4 * lane + 2] = 0; hist[wv][4 * lane + 3] = 0;
    if (lane == 0) s_cnt[wv] = 0;
    __syncthreads();

    const float xi = sx[i], yi = sy[i], zi = sz[i];
    const float sqi = xi * xi + yi * yi + zi * zi;

    // distances + quantize once; 4 points/lane/chunk via b128 LDS reads
    uint qp[30];
    #pragma unroll
    for (int c = 0; c < 30; ++c) qp[c] = 0xFFFFFFFFu;        // sentinel
    #pragma unroll
    for (int c = 0; c < 15; ++c) {
        int j0 = (c << 8) + lane * 4;
        if (j0 < HW) {
            float4 x4 = *(const float4*)&sx[j0];
            float4 y4 = *(const float4*)&sy[j0];
            float4 z4 = *(const float4*)&sz[j0];
            float d0 = fmaxf(sqi + (x4.x * x4.x + y4.x * y4.x + z4.x * z4.x)
                             - 2.0f * (xi * x4.x + yi * y4.x + zi * z4.x), 0.0f);
            float d1 = fmaxf(sqi + (x4.y * x4.y + y4.y * y4.y + z4.y * z4.y)
                             - 2.0f * (xi * x4.y + yi * y4.y + zi * z4.y), 0.0f);
            float d2 = fmaxf(sqi + (x4.z * x4.z + y4.z * y4.z + z4.z * z4.z)
                             - 2.0f * (xi * x4.z + yi * y4.z + zi * z4.z), 0.0f);
            float d3 = fmaxf(sqi + (x4.w * x4.w + y4.w * y4.w + z4.w * z4.w)
                             - 2.0f * (xi * x4.w + yi * y4.w + zi * z4.w), 0.0f);
            uint k0 = (uint)fminf(d0 * 1024.0f, 65535.0f);
            uint k1 = (uint)fminf(d1 * 1024.0f, 65535.0f);
            uint k2 = (uint)fminf(d2 * 1024.0f, 65535.0f);
            uint k3 = (uint)fminf(d3 * 1024.0f, 65535.0f);
            qp[2 * c]     = k0 | (k1 << 16);
            qp[2 * c + 1] = k2 | (k3 << 16);
        }
    }
    #define Q16(c, t) ((qp[2 * (c) + ((t) >> 1)] >> (((t) & 1) << 4)) & 0xFFFFu)

    // pass 1: high byte (wave-private histogram; 0xFF sentinel bin harmless)
    #pragma unroll
    for (int c = 0; c < 15; ++c)
        #pragma unroll
        for (int t = 0; t < 4; ++t) atomicAdd(&hist[wv][Q16(c, t) >> 8], 1u);
    __syncthreads();
    wave_select(&hist[wv][0], &s_bin[wv], &s_want[wv], lane, KNN);
    __syncthreads();
    const uint qT8 = s_bin[wv];
    const uint want2 = s_want[wv];
    __syncthreads();

    // pass 2: low byte among survivors
    #pragma unroll
    for (int c = 0; c < 15; ++c)
        #pragma unroll
        for (int t = 0; t < 4; ++t) {
            uint k = Q16(c, t);
            if ((k >> 8) == qT8) atomicAdd(&hist[wv][k & 255u], 1u);
        }
    __syncthreads();
    wave_select(&hist[wv][0], &s_bin[wv], &s_want[wv], lane, want2);
    __syncthreads();
    const uint qT16 = (qT8 << 8) | s_bin[wv];
    const uint want3 = s_want[wv];

    // collect all strictly-below (sentinels 0xFFFF never pass)
    #pragma unroll
    for (int c = 0; c < 15; ++c)
        #pragma unroll
        for (int t = 0; t < 4; ++t) {
            if (Q16(c, t) < qT16) {
                uint pos = atomicAdd(&s_cnt[wv], 1u);
                if (pos < KNN)
                    idx_out[(size_t)q * KNN + pos] = (c << 8) + lane * 4 + t;
            }
        }
    // ties at qT16: exact (f32bits(d2), index) min, want3 rounds.
    // Per-wave divergent trip counts -> shuffle-only, no barriers below.
    unsigned long long used = 0ULL;                  // bit = c*4+t (< 60)
    const int base = KNN - (int)want3;
    for (int r = 0; r < (int)want3; ++r) {
        unsigned long long best = ~0ULL;
        #pragma unroll
        for (int c = 0; c < 15; ++c) {
            int j0 = (c << 8) + lane * 4;
            if (j0 < HW) {
                float4 x4 = *(const float4*)&sx[j0];
                float4 y4 = *(const float4*)&sy[j0];
                float4 z4 = *(const float4*)&sz[j0];
                float dd[4];
                dd[0] = fmaxf(sqi + (x4.x * x4.x + y4.x * y4.x + z4.x * z4.x)
                              - 2.0f * (xi * x4.x + yi * y4.x + zi * z4.x), 0.0f);
                dd[1] = fmaxf(sqi + (x4.y * x4.y + y4.y * y4.y + z4.y * z4.y)
                              - 2.0f * (xi * x4.y + yi * y4.y + zi * z4.y), 0.0f);
                dd[2] = fmaxf(sqi + (x4.z * x4.z + y4.z * y4.z + z4.z * z4.z)
                              - 2.0f * (xi * x4.z + yi * y4.z + zi * z4.z), 0.0f);
                dd[3] = fmaxf(sqi + (x4.w * x4.w + y4.w * y4.w + z4.w * z4.w)
                              - 2.0f * (xi * x4.w + yi * y4.w + zi * z4.w), 0.0f);
                #pragma unroll
                for (int t = 0; t < 4; ++t) {
                    int slot = c * 4 + t;
                    if (Q16(c, t) == qT16 && !((used >> slot) & 1ULL)) {
                        unsigned long long key =
                            ((unsigned long long)__float_as_uint(dd[t]) << 32)
                            | (uint)(j0 + t);
                        if (key < best) best = key;
                    }
                }
            }
        }
        #pragma unroll
        for (int off = 1; off < 64; off <<= 1) {
            unsigned long long o = __shfl_xor(best, off, 64);
            if (o < best) best = o;
        }
        uint jw = (uint)best;
        if (lane == 0) idx_out[(size_t)q * KNN + base + r] = (int)jw;
        if ((int)((jw & 255u) >> 2) == lane)
            used |= 1ULL << (((jw >> 8) << 2) | (jw & 3u));
    }
    #undef Q16
}

// ---------------------------------------------------------------------------
// setup: weight bf16 conversion (pad-zeroing removed: pad rows of A only
// affect pad rows of C, never read for real outputs; 0xAA poison is finite)
// ---------------------------------------------------------------------------
__global__ __launch_bounds__(256) void setup_kernel(
    const float* __restrict__ mw, const float* __restrict__ rw,
    unsigned short* __restrict__ mo, unsigned short* __restrict__ ro) {
    int i = blockIdx.x * 256 + threadIdx.x;       // grid covers 131072
    if (i < 65536) mo[i] = f2bf(mw[i]);
    ro[i] = f2bf(rw[i]);
}

// ---------------------------------------------------------------------------
// h0 init + passthrough: NH[(n*HW+hw)*512+c] = bf16(cnn[n][c][hw]);
// out[n][c][hw] = cnn[n][c][hw]  (cnn read once)
// ---------------------------------------------------------------------------
__global__ __launch_bounds__(256) void init_h(const float* __restrict__ cnn,
                                              unsigned short* __restrict__ NH,
                                              float* __restrict__ out) {
    __shared__ float tile[32][33];
    const int hw0 = blockIdx.x * 32;
    const int c0 = blockIdx.y * 32;
    const int n = blockIdx.z;
    const int tx = threadIdx.x & 31;
    const int ty = threadIdx.x >> 5;   // 0..7
    const float* __restrict__ src = cnn + (size_t)n * CDIM * HW;
    #pragma unroll
    for (int r = 0; r < 4; ++r) {
        int cc = ty + r * 8;
        int hw = hw0 + tx;
        if (hw < HW) {
            float v = src[(size_t)(c0 + cc) * HW + hw];
            tile[cc][tx] = v;
            out[(size_t)n * (2 * CDIM * HW) + (size_t)(c0 + cc) * HW + hw] = v;
        }
    }
    __syncthreads();
    #pragma unroll
    for (int r = 0; r < 4; ++r) {
        int hh = ty + r * 8;
        int hw = hw0 + hh;
        if (hw < HW) NH[(size_t)(n * HW + hw) * 512 + c0 + tx] = f2bf(tile[tx][hh]);
    }
}

// ---------------------------------------------------------------------------
// bf16 MFMA GEMM: C[m][n] = relu( sum_k A[m][k]*W[n][k] + bias[n] )
// 64x64 block tile, BK=256 (full-K staging: 2 barriers for K=256, 4 for
// K=512). 4 waves, each 32x32 (2x2 frags of 16x16x32). LDS rows padded to
// 264 bf16 (528 B; bank step 4 -> 2-way aliasing in b128 quarter-waves, free).
// mode 0: bf16 store to Cb (ldc). mode 1: fused fp32 transpose-store to
// out[n][256+col][hw] (m = n*HW+hw, 4 acc rows = 4 consecutive hw = float4).
// ---------------------------------------------------------------------------
#define LDKP 264
__global__ __launch_bounds__(256) void gemm_mfma(
    const unsigned short* __restrict__ A, int lda,
    const unsigned short* __restrict__ W, int ldw,
    const float* __restrict__ bias,
    unsigned short* __restrict__ Cb, int ldc,
    float* __restrict__ outp, int mode, int Kk) {
    __shared__ __align__(16) unsigned short As[64 * LDKP];
    __shared__ __align__(16) unsigned short Bs[64 * LDKP];
    const int m0 = blockIdx.x * 64;
    const int n0 = blockIdx.y * 64;
    const int tid = threadIdx.x;
    const int lane = tid & 63;
    const int w = tid >> 6;
    const int wm = (w & 1) * 32;
    const int wn = (w >> 1) * 32;
    const int l15 = lane & 15;
    const int qd = lane >> 4;            // quad 0..3

    floatx4 acc[2][2];
    #pragma unroll
    for (int a = 0; a < 2; ++a)
        #pragma unroll
        for (int b = 0; b < 2; ++b)
            acc[a][b] = (floatx4){0.f, 0.f, 0.f, 0.f};

    const int srow = tid >> 5;           // 0..7
    const int scol = (tid & 31) * 8;     // 0..248 (16B chunks across K=256)

    for (int k0 = 0; k0 < Kk; k0 += 256) {
        if (k0) __syncthreads();
        #pragma unroll
        for (int r8 = 0; r8 < 8; ++r8) {
            int row = r8 * 8 + srow;
            *(float4*)&As[row * LDKP + scol] =
                *(const float4*)&A[(size_t)(m0 + row) * lda + k0 + scol];
            *(float4*)&Bs[row * LDKP + scol] =
                *(const float4*)&W[(size_t)(n0 + row) * ldw + k0 + scol];
        }
        __syncthreads();
        #pragma unroll
        for (int ks = 0; ks < 256; ks += 32) {
            short8 a0 = *(const short8*)&As[(wm + l15) * LDKP + ks + qd * 8];
            short8 a1 = *(const short8*)&As[(wm + 16 + l15) * LDKP + ks + qd * 8];
            short8 b0 = *(const short8*)&Bs[(wn + l15) * LDKP + ks + qd * 8];
            short8 b1 = *(const short8*)&Bs[(wn + 16 + l15) * LDKP + ks + qd * 8];
            acc[0][0] = __builtin_amdgcn_mfma_f32_16x16x32_bf16(a0, b0, acc[0][0], 0, 0, 0);
            acc[0][1] = __builtin_amdgcn_mfma_f32_16x16x32_bf16(a0, b1, acc[0][1], 0, 0, 0);
            acc[1][0] = __builtin_amdgcn_mfma_f32_16x16x32_bf16(a1, b0, acc[1][0], 0, 0, 0);
            acc[1][1] = __builtin_amdgcn_mfma_f32_16x16x32_bf16(a1, b1, acc[1][1], 0, 0, 0);
        }
    }

    #pragma unroll
    for (int in = 0; in < 2; ++in) {
        int col = n0 + wn + in * 16 + l15;
        float bv = bias[col];
        #pragma unroll
        for (int im = 0; im < 2; ++im) {
            int mb = m0 + wm + im * 16 + qd * 4;   // 4-aligned; HW%4==0 so no
            if (mode == 0) {                       // batch straddle in a group
                #pragma unroll
                for (int r = 0; r < 4; ++r)
                    Cb[(size_t)(mb + r) * ldc + col] =
                        f2bf(fmaxf(acc[im][in][r] + bv, 0.0f));
            } else if (mb < M_REAL) {
                int nb = mb / HW;
                int hw = mb - nb * HW;
                float4 o;
                o.x = fmaxf(acc[im][in][0] + bv, 0.0f);
                o.y = fmaxf(acc[im][in][1] + bv, 0.0f);
                o.z = fmaxf(acc[im][in][2] + bv, 0.0f);
                o.w = fmaxf(acc[im][in][3] + bv, 0.0f);
                *(float4*)&outp[(size_t)nb * (2 * CDIM * HW)
                                + (size_t)(CDIM + col) * HW + hw] = o;
            }
        }
    }
}

// ---------------------------------------------------------------------------
// message[q][c] = (1/64)*sum_k T[n*HW+idx[q][k]][c] -> NH right half (bf16)
// wave per query: 32 lanes x 8 cols (uint4 = 16B loads), k parity by
// lane-half, shfl_xor(32) cross-half reduce. Gathered index clamped.
// ---------------------------------------------------------------------------
__global__ __launch_bounds__(256) void gather_mean(const unsigned short* __restrict__ T,
                                                   const int* __restrict__ idx,
                                                   unsigned short* __restrict__ NH) {
    const int q = blockIdx.x * 4 + (threadIdx.x >> 6);
    const int lane = threadIdx.x & 63;
    const int n = q / HW;
    const int half = lane >> 5;           // k parity
    const int c8 = (lane & 31) * 8;       // 8-col strip

    const int nbrL = idx[(size_t)q * KNN + lane];
    float acc[8] = {0, 0, 0, 0, 0, 0, 0, 0};
    #pragma unroll 4
    for (int it = 0; it < 32; ++it) {
        int k = 2 * it + half;
        int j = __shfl(nbrL, k, 64);
        j = min(max(j, 0), HW - 1);       // defensive clamp
        int r = n * HW + j;
        uint4 v = *(const uint4*)&T[(size_t)r * CDIM + c8];
        acc[0] += bf2f((unsigned short)(v.x & 0xFFFFu));
        acc[1] += bf2f((unsigned short)(v.x >> 16));
        acc[2] += bf2f((unsigned short)(v.y & 0xFFFFu));
        acc[3] += bf2f((unsigned short)(v.y >> 16));
        acc[4] += bf2f((unsigned short)(v.z & 0xFFFFu));
        acc[5] += bf2f((unsigned short)(v.z >> 16));
        acc[6] += bf2f((unsigned short)(v.w & 0xFFFFu));
        acc[7] += bf2f((unsigned short)(v.w >> 16));
    }
    #pragma unroll
    for (int c = 0; c < 8; ++c) acc[c] += __shfl_xor(acc[c], 32, 64);
    if (half == 0) {
        uint4 o;
        o.x = (uint)f2bf(acc[0] * (1.0f / KNN)) | ((uint)f2bf(acc[1] * (1.0f / KNN)) << 16);
        o.y = (uint)f2bf(acc[2] * (1.0f / KNN)) | ((uint)f2bf(acc[3] * (1.0f / KNN)) << 16);
        o.z = (uint)f2bf(acc[4] * (1.0f / KNN)) | ((uint)f2bf(acc[5] * (1.0f / KNN)) << 16);
        o.w = (uint)f2bf(acc[6] * (1.0f / KNN)) | ((uint)f2bf(acc[7] * (1.0f / KNN)) << 16);
        *(uint4*)&NH[(size_t)q * 512 + CDIM + c8] = o;
    }
}

extern "C" void kernel_launch(void* const* d_in, const int* in_sizes, int n_in,
                              void* d_out, int out_size, void* d_ws, size_t ws_size,
                              hipStream_t stream) {
    const float* cnn   = (const float*)d_in[0];
    const float* pts   = (const float*)d_in[1];
    const float* mlp_w = (const float*)d_in[2];
    const float* mlp_b = (const float*)d_in[3];
    const float* rnn_w = (const float*)d_in[4];
    const float* rnn_b = (const float*)d_in[5];
    float* out = (float*)d_out;

    // workspace (bf16 pipeline):
    // NHa(7232x512 u16) | NHb(7232x512 u16) | Tb(7232x256 u16)
    // | mlpw_b(65536 u16) | rnnw_b(131072 u16) | idx(7200x64 int)
    unsigned short* NHa    = (unsigned short*)d_ws;
    unsigned short* NHb    = NHa + (size_t)PADM * 512;
    unsigned short* Tb     = NHb + (size_t)PADM * 512;
    unsigned short* mlpw_b = Tb + (size_t)PADM * CDIM;
    unsigned short* rnnw_b = mlpw_b + 65536;
    int*            idx    = (int*)(rnnw_b + 131072);

    setup_kernel<<<512, 256, 0, stream>>>(mlp_w, rnn_w, mlpw_b, rnnw_b);
    topk_kernel<<<M_REAL / QPB, 512, 0, stream>>>(pts, idx);
    init_h<<<dim3(113, 8, NBATCH), 256, 0, stream>>>(cnn, NHa, out);

    unsigned short* cur = NHa;
    unsigned short* nxt = NHb;
    for (int it = 0; it < 3; ++it) {
        // t = relu(mlp_w @ h + mlp_b): A = cur left half, K=256 -> Tb (bf16)
        gemm_mfma<<<dim3(PADM / 64, CDIM / 64), 256, 0, stream>>>(
            cur, 512, mlpw_b, CDIM, mlp_b, Tb, CDIM, nullptr, 0, CDIM);
        // message = mean_k t[idx] -> cur right half
        gather_mean<<<M_REAL / 4, 256, 0, stream>>>(Tb, idx, cur);
        // h' = relu(rnn_w @ [h;msg] + rnn_b), K=512
        if (it < 2) {
            gemm_mfma<<<dim3(PADM / 64, CDIM / 64), 256, 0, stream>>>(
                cur, 512, rnnw_b, 512, rnn_b, nxt, 512, nullptr, 0, 512);
            unsigned short* tmp = cur; cur = nxt; nxt = tmp;
        } else {  // final: fused transpose-store fp32 directly into out
            gemm_mfma<<<dim3(PADM / 64, CDIM / 64), 256, 0, stream>>>(
                cur, 512, rnnw_b, 512, rnn_b, nullptr, 0, out, 1, 512);
        }
    }
}

// Round 7
// 206.904 us; speedup vs baseline: 1.1759x; 1.1759x over previous
//
#include <hip/hip_runtime.h>
#include <stdint.h>

typedef unsigned int uint;
typedef unsigned long long ull;

#define HW 3600
#define NBATCH 2
#define CDIM 256
#define KNN 64
#define M_REAL 7200
#define PADM 7232          // 7200 padded to multiple of 64 (113*64)
#define QPB 8              // topk queries per block (one per wave)

#define TKB 900            // topk blocks
#define IHB 904            // init_h blocks (2 c-tiles each)
#define SUB 64             // setup blocks

using short8  = __attribute__((ext_vector_type(8))) short;
using floatx4 = __attribute__((ext_vector_type(4))) float;

__device__ inline unsigned short f2bf(float f) {   // RNE fp32 -> bf16 bits
    uint u = __float_as_uint(f);
    uint r = u + 0x7FFFu + ((u >> 16) & 1u);
    return (unsigned short)(r >> 16);
}
__device__ inline float bf2f(unsigned short b) {
    return __uint_as_float(((uint)b) << 16);
}

// ---------------------------------------------------------------------------
// wave_select: find threshold byte-bin from a 256-bin wave-private histogram.
// ---------------------------------------------------------------------------
__device__ inline void wave_select(uint* hist, uint* s_bin, uint* s_want,
                                   int lane, uint want) {
    uint h0 = hist[4 * lane + 0], h1 = hist[4 * lane + 1];
    uint h2 = hist[4 * lane + 2], h3 = hist[4 * lane + 3];
    hist[4 * lane + 0] = 0; hist[4 * lane + 1] = 0;
    hist[4 * lane + 2] = 0; hist[4 * lane + 3] = 0;
    uint c4 = h0 + h1 + h2 + h3;
    uint v = c4;
    #pragma unroll
    for (int off = 1; off < 64; off <<= 1) {
        uint o = __shfl_up(v, off, 64);
        if (lane >= off) v += o;
    }
    uint below = v - c4;                 // count in bins < 4*lane
    if (below < want && want <= v) {     // threshold bin is in my 4 bins
        uint b = 4 * lane, c = below;
        if (c + h0 < want) { c += h0; b = 4 * lane + 1;
            if (c + h1 < want) { c += h1; b = 4 * lane + 2;
                if (c + h2 < want) { c += h2; b = 4 * lane + 3; } } }
        *s_bin = b;
        *s_want = want - c;
    }
}

// ---------------------------------------------------------------------------
// Mega-kernel, 512-thread blocks, three independent block-range roles:
//  [0,900)      topk: 8 queries/block (1/wave), AoS float4 points in LDS
//               (1 ds_read_b128 per point vs 3 b32 — round-6 regression
//               causes fixed: ties cached in regs after ONE rescan,
//               histogram atomics predicated on j<HW).
//  [900,1804)   init_h: h0 bf16 transpose into NHa + fp32 passthrough to out
//  [1804,1868)  setup: weight fp32->bf16
// ---------------------------------------------------------------------------
union MegaSmem {
    struct {
        float4 pts[HW];                  // 57600 B (x,y,z,pad)
        uint hist[QPB][256];             // 8192 B
        uint s_bin[QPB], s_want[QPB], s_cnt[QPB];
    } tk;
    struct { float tile[2][32][33]; } ih;
};

__global__ __launch_bounds__(512) void mega_kernel(
    const float* __restrict__ points, int* __restrict__ idx_out,
    const float* __restrict__ cnn, unsigned short* __restrict__ NH,
    float* __restrict__ out,
    const float* __restrict__ mw, const float* __restrict__ rw,
    unsigned short* __restrict__ mo, unsigned short* __restrict__ ro) {
    __shared__ MegaSmem sm;
    const int blk = blockIdx.x;

    if (blk >= TKB + IHB) {
        // ---- setup role ----
        int i0 = (blk - TKB - IHB) * 2048 + threadIdx.x * 4;
        float4 v = *(const float4*)&rw[i0];
        uint2 p;
        p.x = (uint)f2bf(v.x) | ((uint)f2bf(v.y) << 16);
        p.y = (uint)f2bf(v.z) | ((uint)f2bf(v.w) << 16);
        *(uint2*)&ro[i0] = p;
        if (i0 < 65536) {
            float4 m = *(const float4*)&mw[i0];
            p.x = (uint)f2bf(m.x) | ((uint)f2bf(m.y) << 16);
            p.y = (uint)f2bf(m.z) | ((uint)f2bf(m.w) << 16);
            *(uint2*)&mo[i0] = p;
        }
        return;
    }

    if (blk >= TKB) {
        // ---- init_h role: two 32x32 c-tiles per block ----
        const int b = blk - TKB;             // 0..903
        const int n = b / 452;
        const int r = b - n * 452;
        const int hw0 = (r % 113) * 32;
        const int c0 = (r / 113) * 64 + ((threadIdx.x >> 8) << 5);
        const int t8 = threadIdx.x & 255;
        const int tx = t8 & 31;
        const int ty = t8 >> 5;              // 0..7
        float (*tile)[33] = sm.ih.tile[threadIdx.x >> 8];
        const float* __restrict__ src = cnn + (size_t)n * CDIM * HW;
        #pragma unroll
        for (int rr = 0; rr < 4; ++rr) {
            int cc = ty + rr * 8;
            int hw = hw0 + tx;
            if (hw < HW) {
                float v = src[(size_t)(c0 + cc) * HW + hw];
                tile[cc][tx] = v;
                out[(size_t)n * (2 * CDIM * HW) + (size_t)(c0 + cc) * HW + hw] = v;
            }
        }
        __syncthreads();
        #pragma unroll
        for (int rr = 0; rr < 4; ++rr) {
            int hh = ty + rr * 8;
            int hw = hw0 + hh;
            if (hw < HW)
                NH[(size_t)(n * HW + hw) * 512 + c0 + tx] = f2bf(tile[tx][hh]);
        }
        return;
    }

    // ---- topk role ----
    const int wv = threadIdx.x >> 6;
    const int lane = threadIdx.x & 63;
    const int q = blk * QPB + wv;
    const int n = (blk * QPB) / HW;          // batch uniform per block (450 | 8)
    const int i = q - n * HW;

    const float* __restrict__ px = points + (size_t)n * 3 * HW;
    const float* __restrict__ py = px + HW;
    const float* __restrict__ pz = py + HW;

    for (int j = threadIdx.x; j < HW; j += 512)
        sm.tk.pts[j] = make_float4(px[j], py[j], pz[j], 0.0f);
    sm.tk.hist[wv][4 * lane + 0] = 0; sm.tk.hist[wv][4 * lane + 1] = 0;
    sm.tk.hist[wv][4 * lane + 2] = 0; sm.tk.hist[wv][4 * lane + 3] = 0;
    if (lane == 0) sm.tk.s_cnt[wv] = 0;
    __syncthreads();

    float4 pq = sm.tk.pts[i];
    const float xi = pq.x, yi = pq.y, zi = pq.z;
    const float sqi = xi * xi + yi * yi + zi * zi;

    // distances + quantize once (one b128/point); pack q16 pairs (29 VGPRs)
    uint qp[29];
    #pragma unroll
    for (int s = 0; s < 57; ++s) {
        int j = (s << 6) + lane;
        uint q16 = 0xFFFFu;                  // OOB sentinel (strip 56 only)
        if (j < HW) {
            float4 p = sm.tk.pts[j];
            float d2 = fmaxf(sqi + (p.x * p.x + p.y * p.y + p.z * p.z)
                             - 2.0f * (xi * p.x + yi * p.y + zi * p.z), 0.0f);
            q16 = (uint)fminf(d2 * 1024.0f, 65535.0f);
        }
        if (s & 1) qp[s >> 1] |= q16 << 16; else qp[s >> 1] = q16;
    }
    #define Q16(s) ((qp[(s) >> 1] >> (((s) & 1) << 4)) & 0xFFFFu)

    // pass 1: high byte (predicated: no OOB same-bin atomic serialization)
    #pragma unroll
    for (int s = 0; s < 57; ++s) {
        int j = (s << 6) + lane;
        if (j < HW) atomicAdd(&sm.tk.hist[wv][Q16(s) >> 8], 1u);
    }
    __syncthreads();
    wave_select(&sm.tk.hist[wv][0], &sm.tk.s_bin[wv], &sm.tk.s_want[wv], lane, KNN);
    __syncthreads();
    const uint qT8 = sm.tk.s_bin[wv];
    const uint want2 = sm.tk.s_want[wv];
    __syncthreads();

    // pass 2: low byte among survivors
    #pragma unroll
    for (int s = 0; s < 57; ++s) {
        int j = (s << 6) + lane;
        uint k = Q16(s);
        if (j < HW && (k >> 8) == qT8)
            atomicAdd(&sm.tk.hist[wv][k & 255u], 1u);
    }
    __syncthreads();
    wave_select(&sm.tk.hist[wv][0], &sm.tk.s_bin[wv], &sm.tk.s_want[wv], lane, want2);
    __syncthreads();
    const uint qT16 = (qT8 << 8) | sm.tk.s_bin[wv];
    const uint want3 = sm.tk.s_want[wv];

    // collect all strictly-below (exactly KNN-want3 of them; sentinels never pass)
    #pragma unroll
    for (int s = 0; s < 57; ++s) {
        if (Q16(s) < qT16) {
            uint pos = atomicAdd(&sm.tk.s_cnt[wv], 1u);
            if (pos < KNN) idx_out[(size_t)q * KNN + pos] = (s << 6) + lane;
        }
    }

    // ties at qT16: ONE rescan caches exact (f32bits,index) keys in registers
    // (cap 4/lane); shuffle-min rounds run register-only. Ballot fallback to
    // per-round LDS rescan if any lane overflows (correctness guaranteed).
    ull cand[4] = {~0ULL, ~0ULL, ~0ULL, ~0ULL};
    int ncand = 0;
    #pragma unroll
    for (int s = 0; s < 57; ++s) {
        int j = (s << 6) + lane;
        if (j < HW && Q16(s) == qT16) {
            float4 p = sm.tk.pts[j];
            float d2 = fmaxf(sqi + (p.x * p.x + p.y * p.y + p.z * p.z)
                             - 2.0f * (xi * p.x + yi * p.y + zi * p.z), 0.0f);
            ull key = ((ull)__float_as_uint(d2) << 32) | (uint)j;
            if      (ncand == 0) cand[0] = key;
            else if (ncand == 1) cand[1] = key;
            else if (ncand == 2) cand[2] = key;
            else if (ncand == 3) cand[3] = key;
            ++ncand;
        }
    }
    const int base = KNN - (int)want3;
    if (__ballot(ncand > 4) == 0ULL) {
        for (int r = 0; r < (int)want3; ++r) {
            ull best = cand[0] < cand[1] ? cand[0] : cand[1];
            ull b23  = cand[2] < cand[3] ? cand[2] : cand[3];
            best = best < b23 ? best : b23;
            #pragma unroll
            for (int off = 1; off < 64; off <<= 1) {
                ull o = __shfl_xor(best, off, 64);
                if (o < best) best = o;
            }
            if (lane == 0) idx_out[(size_t)q * KNN + base + r] = (int)(uint)best;
            #pragma unroll
            for (int c = 0; c < 4; ++c)
                if (cand[c] == best) cand[c] = ~0ULL;   // unique keys (index)
        }
    } else {
        // rare fallback: per-round rescan from LDS (round-5 semantics)
        ull used = 0ULL;
        for (int r = 0; r < (int)want3; ++r) {
            ull best = ~0ULL;
            #pragma unroll
            for (int s = 0; s < 57; ++s) {
                int j = (s << 6) + lane;
                if (j < HW && Q16(s) == qT16 && !((used >> s) & 1ULL)) {
                    float4 p = sm.tk.pts[j];
                    float d2 = fmaxf(sqi + (p.x * p.x + p.y * p.y + p.z * p.z)
                                     - 2.0f * (xi * p.x + yi * p.y + zi * p.z), 0.0f);
                    ull key = ((ull)__float_as_uint(d2) << 32) | (uint)j;
                    if (key < best) best = key;
                }
            }
            #pragma unroll
            for (int off = 1; off < 64; off <<= 1) {
                ull o = __shfl_xor(best, off, 64);
                if (o < best) best = o;
            }
            uint jw = (uint)best;
            if (lane == 0) idx_out[(size_t)q * KNN + base + r] = (int)jw;
            if ((int)(jw & 63u) == lane) used |= 1ULL << (jw >> 6);
        }
    }
    #undef Q16
}

// ---------------------------------------------------------------------------
// bf16 MFMA GEMM: C[m][n] = relu( sum_k A[m][k]*W[n][k] + bias[n] )
// 64x64 block tile, BK=256 full-K staging. 4 waves, each 32x32 (2x2 frags of
// 16x16x32). LDS rows padded to 264 bf16. mode 0: bf16 store; mode 1: fused
// fp32 transpose-store to out[n][256+col][hw] (4 acc rows = float4 of hw).
// ---------------------------------------------------------------------------
#define LDKP 264
__global__ __launch_bounds__(256) void gemm_mfma(
    const unsigned short* __restrict__ A, int lda,
    const unsigned short* __restrict__ W, int ldw,
    const float* __restrict__ bias,
    unsigned short* __restrict__ Cb, int ldc,
    float* __restrict__ outp, int mode, int Kk) {
    __shared__ __align__(16) unsigned short As[64 * LDKP];
    __shared__ __align__(16) unsigned short Bs[64 * LDKP];
    const int m0 = blockIdx.x * 64;
    const int n0 = blockIdx.y * 64;
    const int tid = threadIdx.x;
    const int lane = tid & 63;
    const int w = tid >> 6;
    const int wm = (w & 1) * 32;
    const int wn = (w >> 1) * 32;
    const int l15 = lane & 15;
    const int qd = lane >> 4;            // quad 0..3

    floatx4 acc[2][2];
    #pragma unroll
    for (int a = 0; a < 2; ++a)
        #pragma unroll
        for (int b = 0; b < 2; ++b)
            acc[a][b] = (floatx4){0.f, 0.f, 0.f, 0.f};

    const int srow = tid >> 5;           // 0..7
    const int scol = (tid & 31) * 8;     // 16B chunks across K=256

    for (int k0 = 0; k0 < Kk; k0 += 256) {
        if (k0) __syncthreads();
        #pragma unroll
        for (int r8 = 0; r8 < 8; ++r8) {
            int row = r8 * 8 + srow;
            *(float4*)&As[row * LDKP + scol] =
                *(const float4*)&A[(size_t)(m0 + row) * lda + k0 + scol];
            *(float4*)&Bs[row * LDKP + scol] =
                *(const float4*)&W[(size_t)(n0 + row) * ldw + k0 + scol];
        }
        __syncthreads();
        #pragma unroll
        for (int ks = 0; ks < 256; ks += 32) {
            short8 a0 = *(const short8*)&As[(wm + l15) * LDKP + ks + qd * 8];
            short8 a1 = *(const short8*)&As[(wm + 16 + l15) * LDKP + ks + qd * 8];
            short8 b0 = *(const short8*)&Bs[(wn + l15) * LDKP + ks + qd * 8];
            short8 b1 = *(const short8*)&Bs[(wn + 16 + l15) * LDKP + ks + qd * 8];
            acc[0][0] = __builtin_amdgcn_mfma_f32_16x16x32_bf16(a0, b0, acc[0][0], 0, 0, 0);
            acc[0][1] = __builtin_amdgcn_mfma_f32_16x16x32_bf16(a0, b1, acc[0][1], 0, 0, 0);
            acc[1][0] = __builtin_amdgcn_mfma_f32_16x16x32_bf16(a1, b0, acc[1][0], 0, 0, 0);
            acc[1][1] = __builtin_amdgcn_mfma_f32_16x16x32_bf16(a1, b1, acc[1][1], 0, 0, 0);
        }
    }

    #pragma unroll
    for (int in = 0; in < 2; ++in) {
        int col = n0 + wn + in * 16 + l15;
        float bv = bias[col];
        #pragma unroll
        for (int im = 0; im < 2; ++im) {
            int mb = m0 + wm + im * 16 + qd * 4;   // 4-aligned; HW%4==0
            if (mode == 0) {
                #pragma unroll
                for (int r = 0; r < 4; ++r)
                    Cb[(size_t)(mb + r) * ldc + col] =
                        f2bf(fmaxf(acc[im][in][r] + bv, 0.0f));
            } else if (mb < M_REAL) {
                int nb = mb / HW;
                int hw = mb - nb * HW;
                float4 o;
                o.x = fmaxf(acc[im][in][0] + bv, 0.0f);
                o.y = fmaxf(acc[im][in][1] + bv, 0.0f);
                o.z = fmaxf(acc[im][in][2] + bv, 0.0f);
                o.w = fmaxf(acc[im][in][3] + bv, 0.0f);
                *(float4*)&outp[(size_t)nb * (2 * CDIM * HW)
                                + (size_t)(CDIM + col) * HW + hw] = o;
            }
        }
    }
}

// ---------------------------------------------------------------------------
// message[q][c] = (1/64)*sum_k T[n*HW+idx[q][k]][c] -> NH right half (bf16)
// wave per query: 32 lanes x 8 cols (uint4 loads), k parity by lane-half,
// shfl_xor(32) cross-half reduce. Gathered index clamped (fault guard).
// ---------------------------------------------------------------------------
__global__ __launch_bounds__(256) void gather_mean(const unsigned short* __restrict__ T,
                                                   const int* __restrict__ idx,
                                                   unsigned short* __restrict__ NH) {
    const int q = blockIdx.x * 4 + (threadIdx.x >> 6);
    const int lane = threadIdx.x & 63;
    const int n = q / HW;
    const int half = lane >> 5;           // k parity
    const int c8 = (lane & 31) * 8;       // 8-col strip

    const int nbrL = idx[(size_t)q * KNN + lane];
    float acc[8] = {0, 0, 0, 0, 0, 0, 0, 0};
    #pragma unroll 4
    for (int it = 0; it < 32; ++it) {
        int k = 2 * it + half;
        int j = __shfl(nbrL, k, 64);
        j = min(max(j, 0), HW - 1);       // defensive clamp
        int r = n * HW + j;
        uint4 v = *(const uint4*)&T[(size_t)r * CDIM + c8];
        acc[0] += bf2f((unsigned short)(v.x & 0xFFFFu));
        acc[1] += bf2f((unsigned short)(v.x >> 16));
        acc[2] += bf2f((unsigned short)(v.y & 0xFFFFu));
        acc[3] += bf2f((unsigned short)(v.y >> 16));
        acc[4] += bf2f((unsigned short)(v.z & 0xFFFFu));
        acc[5] += bf2f((unsigned short)(v.z >> 16));
        acc[6] += bf2f((unsigned short)(v.w & 0xFFFFu));
        acc[7] += bf2f((unsigned short)(v.w >> 16));
    }
    #pragma unroll
    for (int c = 0; c < 8; ++c) acc[c] += __shfl_xor(acc[c], 32, 64);
    if (half == 0) {
        uint4 o;
        o.x = (uint)f2bf(acc[0] * (1.0f / KNN)) | ((uint)f2bf(acc[1] * (1.0f / KNN)) << 16);
        o.y = (uint)f2bf(acc[2] * (1.0f / KNN)) | ((uint)f2bf(acc[3] * (1.0f / KNN)) << 16);
        o.z = (uint)f2bf(acc[4] * (1.0f / KNN)) | ((uint)f2bf(acc[5] * (1.0f / KNN)) << 16);
        o.w = (uint)f2bf(acc[6] * (1.0f / KNN)) | ((uint)f2bf(acc[7] * (1.0f / KNN)) << 16);
        *(uint4*)&NH[(size_t)q * 512 + CDIM + c8] = o;
    }
}

extern "C" void kernel_launch(void* const* d_in, const int* in_sizes, int n_in,
                              void* d_out, int out_size, void* d_ws, size_t ws_size,
                              hipStream_t stream) {
    const float* cnn   = (const float*)d_in[0];
    const float* pts   = (const float*)d_in[1];
    const float* mlp_w = (const float*)d_in[2];
    const float* mlp_b = (const float*)d_in[3];
    const float* rnn_w = (const float*)d_in[4];
    const float* rnn_b = (const float*)d_in[5];
    float* out = (float*)d_out;

    // workspace (bf16 pipeline):
    // NHa(7232x512 u16) | NHb(7232x512 u16) | Tb(7232x256 u16)
    // | mlpw_b(65536 u16) | rnnw_b(131072 u16) | idx(7200x64 int)
    unsigned short* NHa    = (unsigned short*)d_ws;
    unsigned short* NHb    = NHa + (size_t)PADM * 512;
    unsigned short* Tb     = NHb + (size_t)PADM * 512;
    unsigned short* mlpw_b = Tb + (size_t)PADM * CDIM;
    unsigned short* rnnw_b = mlpw_b + 65536;
    int*            idx    = (int*)(rnnw_b + 131072);

    mega_kernel<<<TKB + IHB + SUB, 512, 0, stream>>>(
        pts, idx, cnn, NHa, out, mlp_w, rnn_w, mlpw_b, rnnw_b);

    unsigned short* cur = NHa;
    unsigned short* nxt = NHb;
    for (int it = 0; it < 3; ++it) {
        // t = relu(mlp_w @ h + mlp_b): A = cur left half, K=256 -> Tb (bf16)
        gemm_mfma<<<dim3(PADM / 64, CDIM / 64), 256, 0, stream>>>(
            cur, 512, mlpw_b, CDIM, mlp_b, Tb, CDIM, nullptr, 0, CDIM);
        // message = mean_k t[idx] -> cur right half
        gather_mean<<<M_REAL / 4, 256, 0, stream>>>(Tb, idx, cur);
        // h' = relu(rnn_w @ [h;msg] + rnn_b), K=512
        if (it < 2) {
            gemm_mfma<<<dim3(PADM / 64, CDIM / 64), 256, 0, stream>>>(
                cur, 512, rnnw_b, 512, rnn_b, nxt, 512, nullptr, 0, 512);
            unsigned short* tmp = cur; cur = nxt; nxt = tmp;
        } else {  // final: fused transpose-store fp32 directly into out
            gemm_mfma<<<dim3(PADM / 64, CDIM / 64), 256, 0, stream>>>(
                cur, 512, rnnw_b, 512, rnn_b, nullptr, 0, out, 1, 512);
        }
    }
}